// Round 2
// baseline (3665.070 us; speedup 1.0000x reference)
//
#include <hip/hip_runtime.h>

#define BATCH 2048
#define SEQT  2000
#define H1    51

__device__ __forceinline__ float rl(float v, int lane) {
    return __int_as_float(__builtin_amdgcn_readlane(__float_as_int(v), lane));
}
__device__ __forceinline__ float sigf(float x) {
    return 1.f / (1.f + __expf(-x));
}
__device__ __forceinline__ float tanhfast(float x) {
    return 1.f - 2.f / (__expf(2.f * x) + 1.f);
}

__global__ void __launch_bounds__(64)
__attribute__((amdgpu_waves_per_eu(2, 2)))
lstm_seq_kernel(const float* __restrict__ input,
                const float* __restrict__ W_ih1,
                const float* __restrict__ W_hh1,
                const float* __restrict__ b_ih1,
                const float* __restrict__ b_hh1,
                const float* __restrict__ W_ih3,
                const float* __restrict__ W_hh3,
                const float* __restrict__ b_ih3,
                const float* __restrict__ b_hh3,
                float* __restrict__ out) {
    const int b = blockIdx.x;      // one batch row per wave
    const int j = threadIdx.x;     // lane j owns hidden unit j (j<51)
    const bool act = (j < H1);
    const int js = act ? j : 0;    // lanes >=51 mirror unit 0 (finite, unused)

    // ---- per-unit weights in registers: lane j holds rows {j,51+j,102+j,153+j}
    // packed as (i,f) and (g,o) pairs for v_pk_fma_f32 formation.
    float2 w_if[H1], w_go[H1];
    const float* r_i = W_hh1 + (size_t)(0 * H1 + js) * H1;
    const float* r_f = W_hh1 + (size_t)(1 * H1 + js) * H1;
    const float* r_g = W_hh1 + (size_t)(2 * H1 + js) * H1;
    const float* r_o = W_hh1 + (size_t)(3 * H1 + js) * H1;
#pragma unroll
    for (int k = 0; k < H1; ++k) {
        w_if[k] = make_float2(r_i[k], r_f[k]);
        w_go[k] = make_float2(r_g[k], r_o[k]);
    }
    float2 wihx_if = make_float2(W_ih1[js], W_ih1[H1 + js]);
    float2 wihx_go = make_float2(W_ih1[2 * H1 + js], W_ih1[3 * H1 + js]);
    float2 bias_if = make_float2(b_ih1[js] + b_hh1[js],
                                 b_ih1[H1 + js] + b_hh1[H1 + js]);
    float2 bias_go = make_float2(b_ih1[2 * H1 + js] + b_hh1[2 * H1 + js],
                                 b_ih1[3 * H1 + js] + b_hh1[3 * H1 + js]);
    // lstm3 input weights: inactive lanes contribute 0 to the reduction
    float wih3j[4];
#pragma unroll
    for (int g = 0; g < 4; ++g)
        wih3j[g] = act ? W_ih3[g * H1 + j] : 0.f;
    float whh3[4], b3[4];
#pragma unroll
    for (int g = 0; g < 4; ++g) {
        whh3[g] = W_hh3[g];
        b3[g]   = b_ih3[g] + b_hh3[g];
    }

    float h1v = 0.f, c1v = 0.f;   // unit j state (distributed)
    float h3 = 0.f, c3 = 0.f;     // uniform scalar state

    const size_t rowbase = (size_t)b * SEQT;

    for (int t0 = 0; t0 < SEQT; t0 += 64) {
        const int idx = t0 + j;
        float xv = (idx < SEQT) ? input[rowbase + idx] : 0.f;
        const int tend = (SEQT - t0 < 64) ? (SEQT - t0) : 64;
        float outv = 0.f;

        for (int tt = 0; tt < tend; ++tt) {
            const float xt = rl(xv, tt);

            // ---- LSTM1 gates (packed (i,f) and (g,o)) ----
            float2 a_if, a_go;
            a_if.x = fmaf(xt, wihx_if.x, bias_if.x);
            a_if.y = fmaf(xt, wihx_if.y, bias_if.y);
            a_go.x = fmaf(xt, wihx_go.x, bias_go.x);
            a_go.y = fmaf(xt, wihx_go.y, bias_go.y);
#pragma unroll
            for (int k = 0; k < H1; ++k) {
                const float hk = rl(h1v, k);
                a_if.x = fmaf(hk, w_if[k].x, a_if.x);
                a_if.y = fmaf(hk, w_if[k].y, a_if.y);
                a_go.x = fmaf(hk, w_go[k].x, a_go.x);
                a_go.y = fmaf(hk, w_go[k].y, a_go.y);
            }
            c1v = sigf(a_if.y) * c1v + sigf(a_if.x) * tanhfast(a_go.x);
            h1v = sigf(a_go.y) * tanhfast(c1v);

            // ---- LSTM3 (H3 = 1): reduce c1 @ W_ih3 across lanes ----
            float p0 = c1v * wih3j[0];
            float p1 = c1v * wih3j[1];
            float p2 = c1v * wih3j[2];
            float p3 = c1v * wih3j[3];
#pragma unroll
            for (int m = 1; m < 64; m <<= 1) {
                p0 += __shfl_xor(p0, m);
                p1 += __shfl_xor(p1, m);
                p2 += __shfl_xor(p2, m);
                p3 += __shfl_xor(p3, m);
            }
            const float gi = fmaf(whh3[0], h3, p0) + b3[0];
            const float gf = fmaf(whh3[1], h3, p1) + b3[1];
            const float gg = fmaf(whh3[2], h3, p2) + b3[2];
            const float go = fmaf(whh3[3], h3, p3) + b3[3];
            c3 = sigf(gf) * c3 + sigf(gi) * tanhfast(gg);
            h3 = sigf(go) * tanhfast(c3);

            // lane tt captures this step's uniform c3 (coalesced store later)
            outv = (j == tt) ? c3 : outv;
        }

        if (idx < SEQT) out[rowbase + idx] = outv;
    }
}

extern "C" void kernel_launch(void* const* d_in, const int* in_sizes, int n_in,
                              void* d_out, int out_size, void* d_ws, size_t ws_size,
                              hipStream_t stream) {
    const float* input = (const float*)d_in[0];
    const float* W_ih1 = (const float*)d_in[1];
    const float* W_hh1 = (const float*)d_in[2];
    const float* b_ih1 = (const float*)d_in[3];
    const float* b_hh1 = (const float*)d_in[4];
    const float* W_ih3 = (const float*)d_in[5];
    const float* W_hh3 = (const float*)d_in[6];
    const float* b_ih3 = (const float*)d_in[7];
    const float* b_hh3 = (const float*)d_in[8];
    float* out = (float*)d_out;

    lstm_seq_kernel<<<BATCH, 64, 0, stream>>>(
        input, W_ih1, W_hh1, b_ih1, b_hh1, W_ih3, W_hh3, b_ih3, b_hh3, out);
}